// Round 3
// baseline (963.842 us; speedup 1.0000x reference)
//
#include <hip/hip_runtime.h>
#include <math.h>

// ---------------------------------------------------------------------------
// MPConv round 3: linear-split restructure.
//   xab = x @ [W1a|W1b]  (per-node precompute, bf16)        [MFMA kernel]
//   per edge: acc = [xab_i | xab_j | ea] @ [I;I;W1c] + b1   [MFMA, identity]
//             h = GELU(LN(acc)); Hsum[j] += h; deg[j] += 1  [f32 atomics]
//   out = Hsum @ W2 + deg * b2                              [MFMA kernel]
// ---------------------------------------------------------------------------

using short8 = __attribute__((ext_vector_type(8))) short;
using f32x4  = __attribute__((ext_vector_type(4))) float;

static __device__ __forceinline__ short f2bf(float f) {
    unsigned u = __float_as_uint(f);
    u += 0x7FFFu + ((u >> 16) & 1u);        // round-to-nearest-even
    return (short)(u >> 16);
}

static __device__ __forceinline__ short8 pack8(float4 a, float4 b) {
    short8 r;
    r[0] = f2bf(a.x); r[1] = f2bf(a.y); r[2] = f2bf(a.z); r[3] = f2bf(a.w);
    r[4] = f2bf(b.x); r[5] = f2bf(b.y); r[6] = f2bf(b.z); r[7] = f2bf(b.w);
    return r;
}

// ---- weight prep ----------------------------------------------------------
// WtExt [64][160]: rows of B^T for [I64; I64; W1c]
// Wab   [128][64]: B^T for x @ [W1a | W1b]
// Wt2t  [64][64] : B^T for W2
__global__ void prep_weights2(const float* __restrict__ W1,
                              const float* __restrict__ W2,
                              short* __restrict__ WtExt,
                              short* __restrict__ Wab,
                              short* __restrict__ Wt2t)
{
    int t = blockIdx.x * blockDim.x + threadIdx.x;
    if (t < 64 * 160) {
        int n = t / 160, k = t % 160;
        float v;
        if (k < 64)       v = (k == n) ? 1.0f : 0.0f;
        else if (k < 128) v = ((k - 64) == n) ? 1.0f : 0.0f;
        else              v = W1[(size_t)k * 64 + n];
        WtExt[t] = f2bf(v);
    } else if (t < 64 * 160 + 128 * 64) {
        int t2 = t - 64 * 160;
        int n = t2 / 64, k = t2 % 64;
        float v = (n < 64) ? W1[(size_t)k * 64 + n]
                           : W1[(size_t)(64 + k) * 64 + (n - 64)];
        Wab[t2] = f2bf(v);
    } else if (t < 64 * 160 + 128 * 64 + 64 * 64) {
        int t3 = t - 64 * 160 - 128 * 64;
        int n = t3 / 64, k = t3 % 64;
        Wt2t[t3] = f2bf(W2[(size_t)k * 64 + n]);
    }
}

// ---- xab = x @ [W1a|W1b], stored bf16 [N][128] ---------------------------
__global__ __launch_bounds__(256) void precompute_xab(
    const float* __restrict__ x, const short* __restrict__ Wab,
    short* __restrict__ xab, int N)
{
    const int wave = threadIdx.x >> 6, lane = threadIdx.x & 63;
    const int g = lane >> 4, col = lane & 15;
    const int base = blockIdx.x * 256 + wave * 64;

    short8 af[4][2];
#pragma unroll
    for (int mt = 0; mt < 4; mt++) {
        int row = base + mt * 16 + col;
        row = (row < N) ? row : (N - 1);
#pragma unroll
        for (int ks = 0; ks < 2; ks++) {
            const float* s = x + (size_t)row * 64 + ks * 32 + g * 8;
            af[mt][ks] = pack8(*(const float4*)s, *(const float4*)(s + 4));
        }
    }
#pragma unroll
    for (int half = 0; half < 2; half++) {
        f32x4 acc[4][4];
#pragma unroll
        for (int mt = 0; mt < 4; mt++)
#pragma unroll
            for (int nt = 0; nt < 4; nt++)
                acc[mt][nt] = (f32x4){0.f, 0.f, 0.f, 0.f};
#pragma unroll
        for (int ks = 0; ks < 2; ks++) {
            short8 bf[4];
#pragma unroll
            for (int nt = 0; nt < 4; nt++)
                bf[nt] = *(const short8*)(Wab +
                    (size_t)(half * 64 + col + 16 * nt) * 64 + ks * 32 + g * 8);
#pragma unroll
            for (int mt = 0; mt < 4; mt++)
#pragma unroll
                for (int nt = 0; nt < 4; nt++)
                    acc[mt][nt] = __builtin_amdgcn_mfma_f32_16x16x32_bf16(
                        af[mt][ks], bf[nt], acc[mt][nt], 0, 0, 0);
        }
#pragma unroll
        for (int mt = 0; mt < 4; mt++)
#pragma unroll
            for (int r = 0; r < 4; r++) {
                int node = base + mt * 16 + g * 4 + r;
                if (node < N)
#pragma unroll
                    for (int nt = 0; nt < 4; nt++)
                        xab[(size_t)node * 128 + half * 64 + col + 16 * nt] =
                            f2bf(acc[mt][nt][r]);
            }
    }
}

// ---- per-edge: GEMM1(identity trick) + LN + GELU + scatter h -------------
__global__ __launch_bounds__(256) void mpconv_edge2(
    const short* __restrict__ xab,    // [N][128] bf16
    const int*   __restrict__ ei,     // [2,E]
    const float* __restrict__ ea,     // [E,32]
    const short* __restrict__ WtExt,  // [64][160] bf16
    const float* __restrict__ b1,
    const float* __restrict__ gam,
    const float* __restrict__ bet,
    float*       __restrict__ Hsum,   // [N,64] f32 (zeroed)
    float*       __restrict__ deg,    // [N] f32 (zeroed)
    int E)
{
    const int wave = threadIdx.x >> 6, lane = threadIdx.x & 63;
    const int g = lane >> 4, col = lane & 15;
    const int eb = blockIdx.x * 256 + wave * 64;

    int aedge[4], ii[4], jj[4];
#pragma unroll
    for (int mt = 0; mt < 4; mt++) {
        int e = eb + mt * 16 + col;
        e = (e < E) ? e : (E - 1);
        aedge[mt] = e;
        ii[mt] = ei[e];
        jj[mt] = ei[E + e];
    }

    float b1c[4], gc[4], bc[4];
#pragma unroll
    for (int nt = 0; nt < 4; nt++) {
        int c = col + 16 * nt;
        b1c[nt] = b1[c]; gc[nt] = gam[c]; bc[nt] = bet[c];
    }

    f32x4 acc[4][4];
#pragma unroll
    for (int mt = 0; mt < 4; mt++)
#pragma unroll
        for (int nt = 0; nt < 4; nt++)
            acc[mt][nt] = (f32x4){0.f, 0.f, 0.f, 0.f};

    // ks 0,1: xab[i] (k 0..63); ks 2,3: xab[j] (k 64..127, same col offset)
#pragma unroll
    for (int ks = 0; ks < 4; ks++) {
        const int kk = ks * 32 + g * 8;
        short8 af[4], bf[4];
#pragma unroll
        for (int mt = 0; mt < 4; mt++) {
            int node = (ks < 2) ? ii[mt] : jj[mt];
            af[mt] = *(const short8*)(xab + (size_t)node * 128 + kk);
        }
#pragma unroll
        for (int nt = 0; nt < 4; nt++)
            bf[nt] = *(const short8*)(WtExt + (size_t)(col + 16 * nt) * 160 + kk);
#pragma unroll
        for (int mt = 0; mt < 4; mt++)
#pragma unroll
            for (int nt = 0; nt < 4; nt++)
                acc[mt][nt] = __builtin_amdgcn_mfma_f32_16x16x32_bf16(
                    af[mt], bf[nt], acc[mt][nt], 0, 0, 0);
    }
    {   // ks 4: edge_attr (f32 -> bf16 pack)
        const int kk = 128 + g * 8;
        short8 af[4], bf[4];
#pragma unroll
        for (int mt = 0; mt < 4; mt++) {
            const float* s = ea + (size_t)aedge[mt] * 32 + (kk - 128);
            af[mt] = pack8(*(const float4*)s, *(const float4*)(s + 4));
        }
#pragma unroll
        for (int nt = 0; nt < 4; nt++)
            bf[nt] = *(const short8*)(WtExt + (size_t)(col + 16 * nt) * 160 + kk);
#pragma unroll
        for (int mt = 0; mt < 4; mt++)
#pragma unroll
            for (int nt = 0; nt < 4; nt++)
                acc[mt][nt] = __builtin_amdgcn_mfma_f32_16x16x32_bf16(
                    af[mt], bf[nt], acc[mt][nt], 0, 0, 0);
    }

    // +b1, LN, GELU (in C layout), overwrite acc with h
#pragma unroll
    for (int mt = 0; mt < 4; mt++) {
        float s[4] = {0.f, 0.f, 0.f, 0.f};
        float q[4] = {0.f, 0.f, 0.f, 0.f};
#pragma unroll
        for (int nt = 0; nt < 4; nt++)
#pragma unroll
            for (int r = 0; r < 4; r++) {
                float v = acc[mt][nt][r] + b1c[nt];
                acc[mt][nt][r] = v;
                s[r] += v;
                q[r] += v * v;
            }
#pragma unroll
        for (int m = 1; m < 16; m <<= 1)
#pragma unroll
            for (int r = 0; r < 4; r++) {
                s[r] += __shfl_xor(s[r], m);
                q[r] += __shfl_xor(q[r], m);
            }
#pragma unroll
        for (int r = 0; r < 4; r++) {
            float mu  = s[r] * (1.0f / 64.0f);
            float var = q[r] * (1.0f / 64.0f) - mu * mu;
            float inv = rsqrtf(var + 1e-5f);
#pragma unroll
            for (int nt = 0; nt < 4; nt++) {
                float h = (acc[mt][nt][r] - mu) * inv * gc[nt] + bc[nt];
                acc[mt][nt][r] =
                    0.5f * h * (1.0f + erff(h * 0.70710678118654752f));
            }
        }
    }

    // scatter h and degree
#pragma unroll
    for (int mt = 0; mt < 4; mt++)
#pragma unroll
        for (int r = 0; r < 4; r++) {
            int e = eb + mt * 16 + g * 4 + r;
            if (e < E) {
                int dst = ei[E + e];
                float* hp = Hsum + (size_t)dst * 64 + col;
#pragma unroll
                for (int nt = 0; nt < 4; nt++)
                    unsafeAtomicAdd(hp + 16 * nt, acc[mt][nt][r]);
                if (col == 0) unsafeAtomicAdd(deg + dst, 1.0f);
            }
        }
}

// ---- out = Hsum @ W2 + deg * b2 ------------------------------------------
__global__ __launch_bounds__(256) void final_node(
    const float* __restrict__ Hsum, const float* __restrict__ deg,
    const short* __restrict__ Wt2t, const float* __restrict__ b2,
    float* __restrict__ out, int N)
{
    const int wave = threadIdx.x >> 6, lane = threadIdx.x & 63;
    const int g = lane >> 4, col = lane & 15;
    const int base = blockIdx.x * 256 + wave * 64;

    float b2c[4];
#pragma unroll
    for (int nt = 0; nt < 4; nt++) b2c[nt] = b2[col + 16 * nt];

    f32x4 acc[4][4];
#pragma unroll
    for (int mt = 0; mt < 4; mt++)
#pragma unroll
        for (int nt = 0; nt < 4; nt++)
            acc[mt][nt] = (f32x4){0.f, 0.f, 0.f, 0.f};

#pragma unroll
    for (int ks = 0; ks < 2; ks++) {
        const int kk = ks * 32 + g * 8;
        short8 af[4], bf[4];
#pragma unroll
        for (int mt = 0; mt < 4; mt++) {
            int row = base + mt * 16 + col;
            row = (row < N) ? row : (N - 1);
            const float* s = Hsum + (size_t)row * 64 + kk;
            af[mt] = pack8(*(const float4*)s, *(const float4*)(s + 4));
        }
#pragma unroll
        for (int nt = 0; nt < 4; nt++)
            bf[nt] = *(const short8*)(Wt2t + (size_t)(col + 16 * nt) * 64 + kk);
#pragma unroll
        for (int mt = 0; mt < 4; mt++)
#pragma unroll
            for (int nt = 0; nt < 4; nt++)
                acc[mt][nt] = __builtin_amdgcn_mfma_f32_16x16x32_bf16(
                    af[mt], bf[nt], acc[mt][nt], 0, 0, 0);
    }

#pragma unroll
    for (int mt = 0; mt < 4; mt++)
#pragma unroll
        for (int r = 0; r < 4; r++) {
            int node = base + mt * 16 + g * 4 + r;
            if (node < N) {
                float d = deg[node];
#pragma unroll
                for (int nt = 0; nt < 4; nt++)
                    out[(size_t)node * 64 + col + 16 * nt] =
                        acc[mt][nt][r] + d * b2c[nt];
            }
        }
}

extern "C" void kernel_launch(void* const* d_in, const int* in_sizes, int n_in,
                              void* d_out, int out_size, void* d_ws, size_t ws_size,
                              hipStream_t stream)
{
    const float* x   = (const float*)d_in[0];
    const int*   ei  = (const int*)  d_in[1];
    const float* ea  = (const float*)d_in[2];
    const float* W1  = (const float*)d_in[3];
    const float* b1  = (const float*)d_in[4];
    const float* gam = (const float*)d_in[5];
    const float* bet = (const float*)d_in[6];
    const float* W2  = (const float*)d_in[7];
    const float* b2  = (const float*)d_in[8];
    float* out = (float*)d_out;

    const int E = in_sizes[1] / 2;
    const int N = in_sizes[0] / 64;

    // ---- workspace layout (bytes) ----
    char* ws = (char*)d_ws;
    short* WtExt = (short*)(ws);                       // 64*160*2 = 20480
    short* Wt2t  = (short*)(ws + 20480);               // 64*64*2  = 8192
    short* Wab   = (short*)(ws + 28672);               // 128*64*2 = 16384
    short* xab   = (short*)(ws + 45056);               // N*128*2
    float* Hsum  = (float*)(ws + 45056 + (size_t)N * 256);          // N*64*4
    float* deg   = (float*)(ws + 45056 + (size_t)N * 256 + (size_t)N * 256);

    hipMemsetAsync(Hsum, 0, (size_t)N * 64 * sizeof(float), stream);
    hipMemsetAsync(deg, 0, (size_t)N * sizeof(float), stream);

    {
        int total = 64 * 160 + 128 * 64 + 64 * 64;
        hipLaunchKernelGGL(prep_weights2, dim3((total + 255) / 256), dim3(256),
                           0, stream, W1, W2, WtExt, Wab, Wt2t);
    }
    hipLaunchKernelGGL(precompute_xab, dim3((N + 255) / 256), dim3(256),
                       0, stream, x, Wab, xab, N);
    hipLaunchKernelGGL(mpconv_edge2, dim3((E + 255) / 256), dim3(256),
                       0, stream, xab, ei, ea, WtExt, b1, gam, bet,
                       Hsum, deg, E);
    hipLaunchKernelGGL(final_node, dim3((N + 255) / 256), dim3(256),
                       0, stream, Hsum, deg, Wt2t, b2, out, N);
}